// Round 10
// baseline (276.906 us; speedup 1.0000x reference)
//
#include <hip/hip_runtime.h>

typedef __bf16 bf16x8 __attribute__((ext_vector_type(8)));
typedef float f32x4 __attribute__((ext_vector_type(4)));
typedef unsigned short u16x8 __attribute__((ext_vector_type(8)));
typedef int i32x4 __attribute__((ext_vector_type(4)));

#define M_TOT 8192
#define K_TOT 4096
#define N_TOT 4096
#define BM 256
#define BN 256
#define BK 64
#define NT (K_TOT / BK)   // 64

__device__ __forceinline__ unsigned short f2bf(float f) {
  union { float f; unsigned int u; } v; v.f = f;
  unsigned int u = v.u;
  return (unsigned short)((u + 0x7FFFu + ((u >> 16) & 1u)) >> 16);  // RNE
}

// One kernel, two jobs:
//  blocks [0, 8192):    weight[o][i] = bf16(codebook[o, indices[o,i]])
//  blocks [8192, 24576): x f32 -> bf16
__global__ __launch_bounds__(256) void prep(const float* __restrict__ cb,
                                            const int* __restrict__ idx,
                                            const float* __restrict__ X,
                                            unsigned short* __restrict__ Wb,
                                            unsigned short* __restrict__ Xc) {
  const int b = blockIdx.x;
  if (b < 8192) {
    size_t base = ((size_t)b * 256 + threadIdx.x) * 8;
    const float* crow = cb + ((base >> 12) << 8);
    i32x4 i0 = *(const i32x4*)(idx + base);
    i32x4 i1 = *(const i32x4*)(idx + base + 4);
    u16x8 o;
#pragma unroll
    for (int j = 0; j < 4; ++j) { o[j] = f2bf(crow[i0[j]]); o[4 + j] = f2bf(crow[i1[j]]); }
    *(u16x8*)(Wb + base) = o;
  } else {
    size_t base = ((size_t)(b - 8192) * 256 + threadIdx.x) * 8;
    f32x4 a = *(const f32x4*)(X + base);
    f32x4 c = *(const f32x4*)(X + base + 4);
    u16x8 o;
#pragma unroll
    for (int j = 0; j < 4; ++j) { o[j] = f2bf(a[j]); o[4 + j] = f2bf(c[j]); }
    *(u16x8*)(Xc + base) = o;
  }
}

#define GLDS16(g, l)                                                      \
  __builtin_amdgcn_global_load_lds(                                       \
      (__attribute__((address_space(1))) void*)(g),                       \
      (__attribute__((address_space(3))) void*)(l), 16, 0, 0)

// ============================================================================
// Faithful 8-phase (m201-style) tile: 4 phases x {reads; stage; barrier;
// lgkm0; setprio; 16 MFMA (one 64x32 C-quadrant x K=64); setprio; barrier}.
// Quadrant order (m0n0)(m0n1)(m1n0)(m1n1); per-phase ds_reads 12/4/8/0 with
// cross-phase REGISTER reuse (B-nh0 read @p0 reused @p2; B-nh1 @p1 -> @p3;
// A-mh0 @p0 -> p0,p1; A-mh1 @p2 -> p2,p3). lgkmcnt(8) throttle after the
// 12-read phase. Staging (liveness-proven, = R2): p0: A(t+1)h0 -> other buf;
// p1: A(t+1)h1; p2: B(t+2)h0 -> cur buf (B region LDS-dead after p1);
// p3: B(t+2)h1; boundary vmcnt(4) retires A(t+1)+B(t+1), leaves B(t+2).
// ============================================================================
__global__ __launch_bounds__(512, 2) void gemm8(const unsigned short* __restrict__ A,
                                                const unsigned short* __restrict__ B,
                                                const float* __restrict__ bias,
                                                float* __restrict__ C) {
  __shared__ __attribute__((aligned(128))) char lds[131072];

  const int tid = threadIdx.x;
  const int lane = tid & 63;
  const int wm = (tid >> 6) >> 2;   // 0..1
  const int wn = (tid >> 6) & 3;    // 0..3
  const int lr = lane & 15;

  const int bid = blockIdx.x;                    // nwg = 512 = 8 * 64, bijective
  const int swz = (bid & 7) * 64 + (bid >> 3);
  const int bm = swz >> 4;                       // 0..31
  const int bn = swz & 15;                       // 0..15

  const unsigned short* Ap = A + (size_t)bm * BM * K_TOT;
  const unsigned short* Bp = B + (size_t)bn * BN * K_TOT;

  // staging: 512 thr x 16B = 64 rows/issue, 2 issues per 128-row half
  const int srow = tid >> 3;                              // 0..63
  const int sgcol = (((tid & 7) * 16) ^ ((srow & 7) << 4)) >> 1;  // elem col (inv swizzle)
  const int wavebase = (tid & 448) << 4;                  // wave-uniform LDS base part

  // fragment-read constants (swizzled byte cols for k-halves 0/1)
  const int cs0 = (((lane >> 4) << 4)) ^ ((lr & 7) << 4);
  const int cs1 = (64 + ((lane >> 4) << 4)) ^ ((lr & 7) << 4);
  const int rowA0 = (wm * 128 + lr) * 128;          // byte base of A frags
  const int rowB0 = 32768 + (wn * 64 + lr) * 128;   // byte base of B frags

#define RD(off) (*(const bf16x8*)(lds + (off)))
#define STAGE(GB, TK, RB, LOFF)                                               \
  { _Pragma("unroll")                                                         \
    for (int ii = 0; ii < 2; ++ii) {                                          \
      GLDS16((GB) + (size_t)((RB) + ii * 64 + srow) * K_TOT + (TK) + sgcol,   \
             lds + (LOFF) + ii * 8192 + wavebase);                            \
    } }
#define BARRIER()                       \
  {                                     \
    asm volatile("" ::: "memory");      \
    __builtin_amdgcn_s_barrier();       \
    asm volatile("" ::: "memory");      \
  }
#define LGKM0() asm volatile("s_waitcnt lgkmcnt(0)" ::: "memory")

// 16 MFMA: quadrant (MH, NH) = m-frags MH*4..+3 x n-frags NH*2..+1, K=64.
// AV[r*2+kh], BV[n2*2+kh].
#define MFMA_Q(MH, NH, AV, BV)                                                \
  { __builtin_amdgcn_s_setprio(1);                                            \
    _Pragma("unroll")                                                         \
    for (int r = 0; r < 4; ++r) {                                             \
      _Pragma("unroll")                                                       \
      for (int n2 = 0; n2 < 2; ++n2) {                                        \
        acc[(MH)*4+r][(NH)*2+n2] = __builtin_amdgcn_mfma_f32_16x16x32_bf16(   \
            AV[r*2+0], BV[n2*2+0], acc[(MH)*4+r][(NH)*2+n2], 0, 0, 0);        \
        acc[(MH)*4+r][(NH)*2+n2] = __builtin_amdgcn_mfma_f32_16x16x32_bf16(   \
            AV[r*2+1], BV[n2*2+1], acc[(MH)*4+r][(NH)*2+n2], 0, 0, 0);        \
      }                                                                       \
    }                                                                         \
    __builtin_amdgcn_s_setprio(0); }

#define TILE(T, BO, STG_A, STG_B, VMF, LAST)                                      \
  {                                                                               \
    bf16x8 Aq[8], A2[8], Bn0[4], Bn1[4];                                          \
    /* ---- p0: reads A-mh0 (8) + B-nh0 (4); stage A(T+1)h0 ---- */               \
    _Pragma("unroll") for (int r = 0; r < 4; ++r) {                               \
      Aq[r*2+0] = RD((BO) + rowA0 + r * 2048 + cs0);                              \
      Aq[r*2+1] = RD((BO) + rowA0 + r * 2048 + cs1);                              \
    }                                                                             \
    _Pragma("unroll") for (int n = 0; n < 2; ++n) {                               \
      Bn0[n*2+0] = RD((BO) + rowB0 + n * 2048 + cs0);                             \
      Bn0[n*2+1] = RD((BO) + rowB0 + n * 2048 + cs1);                             \
    }                                                                             \
    if (STG_A) STAGE(Ap, ((T) + 1) * BK, 0, ((BO) ^ 65536) + 0);                  \
    asm volatile("s_waitcnt lgkmcnt(8)" ::: "memory");                            \
    BARRIER(); LGKM0();                                                           \
    MFMA_Q(0, 0, Aq, Bn0);                                                        \
    BARRIER();                                                                    \
    /* ---- p1: reads B-nh1 (4); stage A(T+1)h1 ---- */                           \
    _Pragma("unroll") for (int n = 0; n < 2; ++n) {                               \
      Bn1[n*2+0] = RD((BO) + rowB0 + (2 + n) * 2048 + cs0);                       \
      Bn1[n*2+1] = RD((BO) + rowB0 + (2 + n) * 2048 + cs1);                       \
    }                                                                             \
    if (STG_A) STAGE(Ap, ((T) + 1) * BK, 128, ((BO) ^ 65536) + 16384);            \
    BARRIER(); LGKM0();                                                           \
    MFMA_Q(0, 1, Aq, Bn1);                                                        \
    BARRIER();                                                                    \
    /* ---- p2: reads A-mh1 (8); stage B(T+2)h0 (B LDS-dead after p1) ---- */     \
    _Pragma("unroll") for (int r = 0; r < 4; ++r) {                               \
      A2[r*2+0] = RD((BO) + rowA0 + (4 + r) * 2048 + cs0);                        \
      A2[r*2+1] = RD((BO) + rowA0 + (4 + r) * 2048 + cs1);                        \
    }                                                                             \
    if (STG_B) STAGE(Bp, ((T) + 2) * BK, 0, (BO) + 32768);                        \
    BARRIER(); LGKM0();                                                           \
    MFMA_Q(1, 0, A2, Bn0);                                                        \
    BARRIER();                                                                    \
    /* ---- p3: no reads; stage B(T+2)h1; boundary vmcnt ---- */                  \
    if (STG_B) STAGE(Bp, ((T) + 2) * BK, 128, (BO) + 49152);                      \
    BARRIER();                                                                    \
    MFMA_Q(1, 1, A2, Bn1);                                                        \
    if (!(LAST)) {                                                                \
      asm volatile("s_waitcnt vmcnt(" VMF ")" ::: "memory");                      \
      BARRIER();                                                                  \
    }                                                                             \
  }

  f32x4 acc[8][4] = {};

  // ---- prologue: stage T0 all (A0,A1,B0,B1) + T1.{B0,B1}; vmcnt(4) ----
  STAGE(Ap, 0, 0, 0);
  STAGE(Ap, 0, 128, 16384);
  STAGE(Bp, 0, 0, 32768);
  STAGE(Bp, 0, 128, 49152);
  STAGE(Bp, BK, 0, 65536 + 32768);
  STAGE(Bp, BK, 128, 65536 + 49152);
  asm volatile("s_waitcnt vmcnt(4)" ::: "memory");  // T0 landed; T1.B in flight
  BARRIER();

  // main loop: tiles 0..NT-3 fully pipelined; last two tiles specialized
  for (int t = 0; t < NT - 2; t += 2) {
    TILE(t,     0,     1, 1, "4", 0);
    TILE(t + 1, 65536, 1, 1, "4", 0);
  }
  TILE(NT - 2, 0,     1, 0, "0", 0);
  TILE(NT - 1, 65536, 0, 0, "0", 1);

  // ---- epilogue: C = acc + bias ----
  const int lg4 = (lane >> 4) << 2;
#pragma unroll
  for (int nf = 0; nf < 4; ++nf) {
    const int col = bn * BN + wn * 64 + nf * 16 + lr;
    const float bv = bias[col];
#pragma unroll
    for (int mf = 0; mf < 8; ++mf) {
      const int row0 = bm * BM + wm * 128 + mf * 16 + lg4;
      float* cp = C + (size_t)row0 * N_TOT + col;
#pragma unroll
      for (int j = 0; j < 4; ++j) cp[(size_t)j * N_TOT] = acc[mf][nf][j] + bv;
    }
  }
#undef RD
#undef STAGE
#undef BARRIER
#undef LGKM0
#undef MFMA_Q
#undef TILE
}

extern "C" void kernel_launch(void* const* d_in, const int* in_sizes, int n_in,
                              void* d_out, int out_size, void* d_ws, size_t ws_size,
                              hipStream_t stream) {
  const float* x    = (const float*)d_in[0];   // [4,2048,4096] f32
  const float* cb   = (const float*)d_in[1];   // [4096,256]   f32
  const float* bias = (const float*)d_in[2];   // [4096]       f32
  const int*   idx  = (const int*)d_in[3];     // [4096,4096]  int

  float* out = (float*)d_out;                  // [4,2048,4096] f32

  unsigned short* Wb = (unsigned short*)d_ws;                                      // 32 MB
  unsigned short* Xc = (unsigned short*)((char*)d_ws + (size_t)N_TOT * K_TOT * 2); // 64 MB

  prep<<<24576, 256, 0, stream>>>(cb, idx, x, Wb, Xc);
  gemm8<<<512, 512, 0, stream>>>(Xc, Wb, bias, out);
}